// Round 1
// baseline (869.999 us; speedup 1.0000x reference)
//
#include <hip/hip_runtime.h>

#define LAT 64

// ---------- graph build ----------

__global__ void count_deg_k(const int* __restrict__ eu, const int* __restrict__ ei,
                            int* __restrict__ deg, int E, int U) {
    int e = blockIdx.x * blockDim.x + threadIdx.x;
    if (e >= E) return;
    atomicAdd(&deg[eu[e]], 1);
    atomicAdd(&deg[ei[e] + U], 1);
}

// inclusive scan within 1024-chunks; chunk totals to partial[]
__global__ void scan_chunk_k(const int* __restrict__ deg, int* __restrict__ incl,
                             int* __restrict__ partial, int N) {
    __shared__ int s[1024];
    int t = threadIdx.x;
    int i = blockIdx.x * 1024 + t;
    int v = (i < N) ? deg[i] : 0;
    s[t] = v;
    __syncthreads();
    for (int off = 1; off < 1024; off <<= 1) {
        int add = (t >= off) ? s[t - off] : 0;
        __syncthreads();
        s[t] += add;
        __syncthreads();
    }
    if (i < N) incl[i] = s[t];
    if (t == 1023) partial[blockIdx.x] = s[1023];
}

__global__ void scan_partial_k(const int* __restrict__ partial, int* __restrict__ base, int NB) {
    if (blockIdx.x == 0 && threadIdx.x == 0) {
        int run = 0;
        for (int b = 0; b < NB; ++b) { base[b] = run; run += partial[b]; }
    }
}

// incl (in offs_io) -> exclusive offsets; init cursor; compute dinv
__global__ void finalize_k(const int* __restrict__ deg, const int* __restrict__ base,
                           int* offs_io, int* __restrict__ cursor,
                           float* __restrict__ dinv, int N) {
    int i = blockIdx.x * blockDim.x + threadIdx.x;
    if (i >= N) return;
    int d = deg[i];
    int excl = offs_io[i] - d + base[i >> 10];
    offs_io[i] = excl;
    cursor[i] = excl;
    dinv[i] = (d > 0) ? rsqrtf((float)d) : 0.0f;
}

__global__ void fill_csr_k(const int* __restrict__ eu, const int* __restrict__ ei,
                           int* __restrict__ cursor, int* __restrict__ col, int E, int U) {
    int e = blockIdx.x * blockDim.x + threadIdx.x;
    if (e >= E) return;
    int u = eu[e], it = ei[e] + U;
    int p = atomicAdd(&cursor[u], 1);
    col[p] = it;
    int q = atomicAdd(&cursor[it], 1);
    col[q] = u;
}

// ---------- embedding init ----------

// y0 = dinv * e0 over all N*64 elements
__global__ void init_y_k(const float* __restrict__ ue, const float* __restrict__ ie,
                         const float* __restrict__ dinv, float* __restrict__ y,
                         int N, int U) {
    int idx = blockIdx.x * blockDim.x + threadIdx.x;
    if (idx >= N * LAT) return;
    int node = idx >> 6;
    float e = (node < U) ? ue[idx] : ie[idx - U * LAT];
    y[idx] = dinv[node] * e;
}

// query accumulator initialized with e0 at the 2B queried nodes
__global__ void init_q_k(const float* __restrict__ ue, const float* __restrict__ ie,
                         const int* __restrict__ users, const int* __restrict__ items,
                         float* __restrict__ qacc, int B, int U) {
    int wave = blockIdx.x * (blockDim.x >> 6) + (threadIdx.x >> 6);
    int lane = threadIdx.x & 63;
    if (wave >= 2 * B) return;
    int node = (wave < B) ? users[wave] : (items[wave - B] + U);
    float e = (node < U) ? ue[node * LAT + lane] : ie[(node - U) * LAT + lane];
    qacc[wave * LAT + lane] = e;
}

// ---------- propagation: one wave per node, lane = feature ----------

__global__ void __launch_bounds__(256)
prop_k(const int* __restrict__ offs, const int* __restrict__ deg,
       const int* __restrict__ col, const float* __restrict__ dinv,
       const float* __restrict__ yin, float* __restrict__ yout, int N) {
    int wave = blockIdx.x * (blockDim.x >> 6) + (threadIdx.x >> 6);
    int lane = threadIdx.x & 63;
    if (wave >= N) return;
    int start = offs[wave];
    int len = deg[wave];
    float s = 0.0f;
    for (int b = 0; b < len; b += 64) {
        int kk = b + lane;
        int cidx = (kk < len) ? col[start + kk] : 0;  // coalesced batch load of cols
        int m = min(64, len - b);
        int j = 0;
        for (; j + 4 <= m; j += 4) {
            int c0 = __shfl(cidx, j);
            int c1 = __shfl(cidx, j + 1);
            int c2 = __shfl(cidx, j + 2);
            int c3 = __shfl(cidx, j + 3);
            float v0 = yin[c0 * LAT + lane];
            float v1 = yin[c1 * LAT + lane];
            float v2 = yin[c2 * LAT + lane];
            float v3 = yin[c3 * LAT + lane];
            s += v0; s += v1; s += v2; s += v3;
        }
        for (; j < m; ++j) {
            int c = __shfl(cidx, j);
            s += yin[c * LAT + lane];
        }
    }
    float di = dinv[wave];
    // x_next = di * s ; y_next = di * x_next
    yout[wave * LAT + lane] = di * (di * s);
}

// after each prop: qacc += x = y / dinv at queried nodes
__global__ void qgather_k(const float* __restrict__ y, const float* __restrict__ dinv,
                          const int* __restrict__ users, const int* __restrict__ items,
                          float* __restrict__ qacc, int B, int U) {
    int wave = blockIdx.x * (blockDim.x >> 6) + (threadIdx.x >> 6);
    int lane = threadIdx.x & 63;
    if (wave >= 2 * B) return;
    int node = (wave < B) ? users[wave] : (items[wave - B] + U);
    float di = dinv[node];
    float r = (di > 0.0f) ? (1.0f / di) : 0.0f;
    qacc[wave * LAT + lane] += y[node * LAT + lane] * r;
}

// gamma[b] = dot(qacc[b], qacc[b+B]) / 25
__global__ void gamma_k(const float* __restrict__ qacc, float* __restrict__ out, int B) {
    int wave = blockIdx.x * (blockDim.x >> 6) + (threadIdx.x >> 6);
    int lane = threadIdx.x & 63;
    if (wave >= B) return;
    float p = qacc[wave * LAT + lane] * qacc[(wave + B) * LAT + lane];
#pragma unroll
    for (int off = 32; off > 0; off >>= 1) p += __shfl_down(p, off);
    if (lane == 0) out[wave] = p * (1.0f / 25.0f);
}

extern "C" void kernel_launch(void* const* d_in, const int* in_sizes, int n_in,
                              void* d_out, int out_size, void* d_ws, size_t ws_size,
                              hipStream_t stream) {
    const float* ue = (const float*)d_in[0];
    const float* ie = (const float*)d_in[1];
    const int* edge = (const int*)d_in[2];
    const int* users = (const int*)d_in[3];
    const int* items = (const int*)d_in[4];

    const int U = in_sizes[0] / LAT;
    const int I = in_sizes[1] / LAT;
    const int N = U + I;
    const int E = in_sizes[2] / 2;
    const int B = in_sizes[3];
    const int* eu = edge;
    const int* ei = edge + E;

    char* ws = (char*)d_ws;
    size_t off = 0;
    auto alloc = [&](size_t bytes) -> void* {
        void* p = ws + off;
        off += (bytes + 255) & ~(size_t)255;
        return p;
    };
    int*   deg     = (int*)alloc((size_t)4 * N);
    int*   offs    = (int*)alloc((size_t)4 * N);
    int*   cursor  = (int*)alloc((size_t)4 * N);
    float* dinv    = (float*)alloc((size_t)4 * N);
    int*   partial = (int*)alloc(4 * 1024);
    int*   base    = (int*)alloc(4 * 1024);
    int*   col     = (int*)alloc((size_t)8 * E);           // 2E ints
    float* yA      = (float*)alloc((size_t)4 * N * LAT);
    float* yB      = (float*)alloc((size_t)4 * N * LAT);
    float* qacc    = (float*)alloc((size_t)4 * 2 * B * LAT);

    hipMemsetAsync(deg, 0, (size_t)4 * N, stream);

    const int tb = 256;
    count_deg_k<<<(E + tb - 1) / tb, tb, 0, stream>>>(eu, ei, deg, E, U);

    int NB = (N + 1023) / 1024;
    scan_chunk_k<<<NB, 1024, 0, stream>>>(deg, offs, partial, N);
    scan_partial_k<<<1, 64, 0, stream>>>(partial, base, NB);
    finalize_k<<<(N + tb - 1) / tb, tb, 0, stream>>>(deg, base, offs, cursor, dinv, N);
    fill_csr_k<<<(E + tb - 1) / tb, tb, 0, stream>>>(eu, ei, cursor, col, E, U);

    init_y_k<<<(N * LAT + tb - 1) / tb, tb, 0, stream>>>(ue, ie, dinv, yA, N, U);
    const int wpb = tb / 64;
    init_q_k<<<(2 * B + wpb - 1) / wpb, tb, 0, stream>>>(ue, ie, users, items, qacc, B, U);

    int pgrid = (N + wpb - 1) / wpb;
    int qgrid = (2 * B + wpb - 1) / wpb;

    prop_k<<<pgrid, tb, 0, stream>>>(offs, deg, col, dinv, yA, yB, N);
    qgather_k<<<qgrid, tb, 0, stream>>>(yB, dinv, users, items, qacc, B, U);
    prop_k<<<pgrid, tb, 0, stream>>>(offs, deg, col, dinv, yB, yA, N);
    qgather_k<<<qgrid, tb, 0, stream>>>(yA, dinv, users, items, qacc, B, U);
    prop_k<<<pgrid, tb, 0, stream>>>(offs, deg, col, dinv, yA, yB, N);
    qgather_k<<<qgrid, tb, 0, stream>>>(yB, dinv, users, items, qacc, B, U);
    prop_k<<<pgrid, tb, 0, stream>>>(offs, deg, col, dinv, yB, yA, N);
    qgather_k<<<qgrid, tb, 0, stream>>>(yA, dinv, users, items, qacc, B, U);

    gamma_k<<<(B + wpb - 1) / wpb, tb, 0, stream>>>(qacc, (float*)d_out, B);
}

// Round 3
// 776.689 us; speedup vs baseline: 1.1201x; 1.1201x over previous
//
#include <hip/hip_runtime.h>

#define LAT 64
#define BSHIFT 13   // 8192-node buckets for the CSR fill scatter

// ---------- graph build ----------

__global__ void count_deg_k(const int* __restrict__ eu, const int* __restrict__ ei,
                            int* __restrict__ deg, int E, int U) {
    int e = blockIdx.x * blockDim.x + threadIdx.x;
    if (e >= E) return;
    atomicAdd(&deg[eu[e]], 1);
    atomicAdd(&deg[ei[e] + U], 1);
}

// inclusive scan within 1024-chunks; chunk totals to partial[]
__global__ void scan_chunk_k(const int* __restrict__ deg, int* __restrict__ incl,
                             int* __restrict__ partial, int N) {
    __shared__ int s[1024];
    int t = threadIdx.x;
    int i = blockIdx.x * 1024 + t;
    int v = (i < N) ? deg[i] : 0;
    s[t] = v;
    __syncthreads();
    for (int off = 1; off < 1024; off <<= 1) {
        int add = (t >= off) ? s[t - off] : 0;
        __syncthreads();
        s[t] += add;
        __syncthreads();
    }
    if (i < N) incl[i] = s[t];
    if (t == 1023) partial[blockIdx.x] = s[1023];
}

__global__ void scan_partial_k(const int* __restrict__ partial, int* __restrict__ base, int NB) {
    if (blockIdx.x == 0 && threadIdx.x == 0) {
        int run = 0;
        for (int b = 0; b < NB; ++b) { base[b] = run; run += partial[b]; }
    }
}

// incl (in offs_io) -> exclusive offsets; init cursor; compute dinv
__global__ void finalize_k(const int* __restrict__ deg, const int* __restrict__ base,
                           int* offs_io, int* __restrict__ cursor,
                           float* __restrict__ dinv, int N) {
    int i = blockIdx.x * blockDim.x + threadIdx.x;
    if (i >= N) return;
    int d = deg[i];
    int excl = offs_io[i] - d + base[i >> 10];
    offs_io[i] = excl;
    cursor[i] = excl;
    dinv[i] = (d > 0) ? rsqrtf((float)d) : 0.0f;
}

// Bucketed scatter: pass p only writes rows in [p<<BSHIFT, (p+1)<<BSHIFT),
// keeping the active cursor (~32KB) and col (~1MB) windows cache-resident so
// write-allocate lines are fully populated before eviction.
__global__ void fill_csr_bucketed_k(const int* __restrict__ eu, const int* __restrict__ ei,
                                    int* __restrict__ cursor, int* __restrict__ col,
                                    int E, int U, int passes) {
    int tid = blockIdx.x * blockDim.x + threadIdx.x;
    int stride = gridDim.x * blockDim.x;
    int E2 = 2 * E;
    for (int p = 0; p < passes; ++p) {
        for (int d = tid; d < E2; d += stride) {
            int r;
            if (d < E) r = eu[d];
            else       r = ei[d - E] + U;
            if ((r >> BSHIFT) != p) continue;
            int c = (d < E) ? (ei[d] + U) : eu[d - E];
            int pos = atomicAdd(&cursor[r], 1);
            col[pos] = c;
        }
    }
}

// ---------- embedding init ----------

__global__ void init_y_k(const float* __restrict__ ue, const float* __restrict__ ie,
                         const float* __restrict__ dinv, float* __restrict__ y,
                         int N, int U) {
    int idx = blockIdx.x * blockDim.x + threadIdx.x;
    if (idx >= N * LAT) return;
    int node = idx >> 6;
    float e = (node < U) ? ue[idx] : ie[idx - U * LAT];
    y[idx] = dinv[node] * e;
}

__global__ void init_q_k(const float* __restrict__ ue, const float* __restrict__ ie,
                         const int* __restrict__ users, const int* __restrict__ items,
                         float* __restrict__ qacc, int B, int U) {
    int wave = blockIdx.x * (blockDim.x >> 6) + (threadIdx.x >> 6);
    int lane = threadIdx.x & 63;
    if (wave >= 2 * B) return;
    int node = (wave < B) ? users[wave] : (items[wave - B] + U);
    float e = (node < U) ? ue[node * LAT + lane] : ie[(node - U) * LAT + lane];
    qacc[wave * LAT + lane] = e;
}

// ---------- propagation: one wave per node; 4 groups x 16 lanes x float4 ----------
// Each group of 16 lanes covers one neighbor row as 16 float4s -> one
// global_load_dwordx4 instruction gathers 4 neighbor rows (1KB) per issue.
// NOTE: inner loop trip count is wave-uniform; __shfl executes with ALL lanes
// active (divergent __shfl on CDNA reads garbage from inactive source lanes —
// that was the R2 bug). Only the accumulate is predicated.

__global__ void __launch_bounds__(256)
prop4_k(const int* __restrict__ offs, const int* __restrict__ deg,
        const int* __restrict__ col, const float* __restrict__ dinv,
        const float* __restrict__ yin, float* __restrict__ yout, int N) {
    int wave = blockIdx.x * (blockDim.x >> 6) + (threadIdx.x >> 6);
    int lane = threadIdx.x & 63;
    if (wave >= N) return;
    int g = lane >> 4;        // group 0..3: which neighbor (mod 4)
    int t = lane & 15;        // float4 slot within the row
    int start = offs[wave];
    int len = deg[wave];
    const float4* y4 = (const float4*)yin;
    float sx = 0.f, sy = 0.f, sz = 0.f, sw = 0.f;
    for (int b = 0; b < len; b += 64) {
        int kk = b + lane;
        int cidx = (kk < len) ? col[start + kk] : 0;   // coalesced batch of cols
        int m = min(64, len - b);                       // wave-uniform
        int nb = (m + 3) >> 2;                          // wave-uniform trip count
        for (int it = 0; it < nb; ++it) {
            int j = (it << 2) + g;                      // varies per group
            int jj = (j < m) ? j : 0;                   // valid lane index for all
            int c = __shfl(cidx, jj);                   // all 64 lanes active here
            float4 v = y4[c * 16 + t];
            if (j < m) { sx += v.x; sy += v.y; sz += v.z; sw += v.w; }
        }
    }
    // reduce across the 4 groups (lanes t, t+16, t+32, t+48)
    sx += __shfl_xor(sx, 16); sy += __shfl_xor(sy, 16);
    sz += __shfl_xor(sz, 16); sw += __shfl_xor(sw, 16);
    sx += __shfl_xor(sx, 32); sy += __shfl_xor(sy, 32);
    sz += __shfl_xor(sz, 32); sw += __shfl_xor(sw, 32);
    if (g == 0) {
        float di = dinv[wave];
        float f = di * di;
        float4 r;
        r.x = f * sx; r.y = f * sy; r.z = f * sz; r.w = f * sw;
        ((float4*)yout)[wave * 16 + t] = r;
    }
}

// after each prop: qacc += x = y / dinv at queried nodes
__global__ void qgather_k(const float* __restrict__ y, const float* __restrict__ dinv,
                          const int* __restrict__ users, const int* __restrict__ items,
                          float* __restrict__ qacc, int B, int U) {
    int wave = blockIdx.x * (blockDim.x >> 6) + (threadIdx.x >> 6);
    int lane = threadIdx.x & 63;
    if (wave >= 2 * B) return;
    int node = (wave < B) ? users[wave] : (items[wave - B] + U);
    float di = dinv[node];
    float r = (di > 0.0f) ? (1.0f / di) : 0.0f;
    qacc[wave * LAT + lane] += y[node * LAT + lane] * r;
}

// gamma[b] = dot(qacc[b], qacc[b+B]) / 25
__global__ void gamma_k(const float* __restrict__ qacc, float* __restrict__ out, int B) {
    int wave = blockIdx.x * (blockDim.x >> 6) + (threadIdx.x >> 6);
    int lane = threadIdx.x & 63;
    if (wave >= B) return;
    float p = qacc[wave * LAT + lane] * qacc[(wave + B) * LAT + lane];
#pragma unroll
    for (int off = 32; off > 0; off >>= 1) p += __shfl_down(p, off);
    if (lane == 0) out[wave] = p * (1.0f / 25.0f);
}

extern "C" void kernel_launch(void* const* d_in, const int* in_sizes, int n_in,
                              void* d_out, int out_size, void* d_ws, size_t ws_size,
                              hipStream_t stream) {
    const float* ue = (const float*)d_in[0];
    const float* ie = (const float*)d_in[1];
    const int* edge = (const int*)d_in[2];
    const int* users = (const int*)d_in[3];
    const int* items = (const int*)d_in[4];

    const int U = in_sizes[0] / LAT;
    const int I = in_sizes[1] / LAT;
    const int N = U + I;
    const int E = in_sizes[2] / 2;
    const int B = in_sizes[3];
    const int* eu = edge;
    const int* ei = edge + E;

    char* ws = (char*)d_ws;
    size_t off = 0;
    auto alloc = [&](size_t bytes) -> void* {
        void* p = ws + off;
        off += (bytes + 255) & ~(size_t)255;
        return p;
    };
    int*   deg     = (int*)alloc((size_t)4 * N);
    int*   offs    = (int*)alloc((size_t)4 * N);
    int*   cursor  = (int*)alloc((size_t)4 * N);
    float* dinv    = (float*)alloc((size_t)4 * N);
    int*   partial = (int*)alloc(4 * 1024);
    int*   base    = (int*)alloc(4 * 1024);
    int*   col     = (int*)alloc((size_t)8 * E);           // 2E ints
    float* yA      = (float*)alloc((size_t)4 * N * LAT);
    float* yB      = (float*)alloc((size_t)4 * N * LAT);
    float* qacc    = (float*)alloc((size_t)4 * 2 * B * LAT);

    hipMemsetAsync(deg, 0, (size_t)4 * N, stream);

    const int tb = 256;
    count_deg_k<<<(E + tb - 1) / tb, tb, 0, stream>>>(eu, ei, deg, E, U);

    int NB = (N + 1023) / 1024;
    scan_chunk_k<<<NB, 1024, 0, stream>>>(deg, offs, partial, N);
    scan_partial_k<<<1, 64, 0, stream>>>(partial, base, NB);
    finalize_k<<<(N + tb - 1) / tb, tb, 0, stream>>>(deg, base, offs, cursor, dinv, N);

    int passes = (N + (1 << BSHIFT) - 1) >> BSHIFT;
    fill_csr_bucketed_k<<<2048, tb, 0, stream>>>(eu, ei, cursor, col, E, U, passes);

    init_y_k<<<(N * LAT + tb - 1) / tb, tb, 0, stream>>>(ue, ie, dinv, yA, N, U);
    const int wpb = tb / 64;
    init_q_k<<<(2 * B + wpb - 1) / wpb, tb, 0, stream>>>(ue, ie, users, items, qacc, B, U);

    int pgrid = (N + wpb - 1) / wpb;
    int qgrid = (2 * B + wpb - 1) / wpb;

    prop4_k<<<pgrid, tb, 0, stream>>>(offs, deg, col, dinv, yA, yB, N);
    qgather_k<<<qgrid, tb, 0, stream>>>(yB, dinv, users, items, qacc, B, U);
    prop4_k<<<pgrid, tb, 0, stream>>>(offs, deg, col, dinv, yB, yA, N);
    qgather_k<<<qgrid, tb, 0, stream>>>(yA, dinv, users, items, qacc, B, U);
    prop4_k<<<pgrid, tb, 0, stream>>>(offs, deg, col, dinv, yA, yB, N);
    qgather_k<<<qgrid, tb, 0, stream>>>(yB, dinv, users, items, qacc, B, U);
    prop4_k<<<pgrid, tb, 0, stream>>>(offs, deg, col, dinv, yB, yA, N);
    qgather_k<<<qgrid, tb, 0, stream>>>(yA, dinv, users, items, qacc, B, U);

    gamma_k<<<(B + wpb - 1) / wpb, tb, 0, stream>>>(qacc, (float*)d_out, B);
}

// Round 4
// 762.070 us; speedup vs baseline: 1.1416x; 1.0192x over previous
//
#include <hip/hip_runtime.h>

#define LAT 64
#define NXCD 8   // MI355X XCDs; blockIdx % 8 -> XCD (perf heuristic only)

// ---------- graph build ----------

// XCD-bucketed degree count: blocks with the same (blockIdx&7) handle one
// exclusive row range, so atomic traffic stays in one XCD's L2 window.
__global__ void count_deg_bucket_k(const int* __restrict__ eu, const int* __restrict__ ei,
                                   int* __restrict__ deg, int E, int U, int N, int bucketN) {
    int xcd = blockIdx.x & (NXCD - 1);
    int lo = xcd * bucketN;
    int hi = min(N, lo + bucketN);
    int tid = (blockIdx.x >> 3) * blockDim.x + threadIdx.x;
    int stride = (gridDim.x >> 3) * blockDim.x;
    int E2 = 2 * E;
    for (int d = tid; d < E2; d += stride) {
        int r = (d < E) ? eu[d] : (ei[d - E] + U);
        if (r >= lo && r < hi) atomicAdd(&deg[r], 1);
    }
}

// inclusive scan within 1024-chunks; chunk totals to partial[]
__global__ void scan_chunk_k(const int* __restrict__ deg, int* __restrict__ incl,
                             int* __restrict__ partial, int N) {
    __shared__ int s[1024];
    int t = threadIdx.x;
    int i = blockIdx.x * 1024 + t;
    int v = (i < N) ? deg[i] : 0;
    s[t] = v;
    __syncthreads();
    for (int off = 1; off < 1024; off <<= 1) {
        int add = (t >= off) ? s[t - off] : 0;
        __syncthreads();
        s[t] += add;
        __syncthreads();
    }
    if (i < N) incl[i] = s[t];
    if (t == 1023) partial[blockIdx.x] = s[1023];
}

__global__ void scan_partial_k(const int* __restrict__ partial, int* __restrict__ base, int NB) {
    if (blockIdx.x == 0 && threadIdx.x == 0) {
        int run = 0;
        for (int b = 0; b < NB; ++b) { base[b] = run; run += partial[b]; }
    }
}

// incl (in offs_io) -> exclusive offsets; init cursor; compute dinv
__global__ void finalize_k(const int* __restrict__ deg, const int* __restrict__ base,
                           int* offs_io, int* __restrict__ cursor,
                           float* __restrict__ dinv, int N) {
    int i = blockIdx.x * blockDim.x + threadIdx.x;
    if (i >= N) return;
    int d = deg[i];
    int excl = offs_io[i] - d + base[i >> 10];
    offs_io[i] = excl;
    cursor[i] = excl;
    dinv[i] = (d > 0) ? rsqrtf((float)d) : 0.0f;
}

// XCD-exclusive scatter: all writes to a given col[] line come from blocks on
// one XCD, so lines are fully assembled in that XCD's L2 before writeback
// (R3's cross-XCD partial-line evictions caused 173MB of HBM writes).
__global__ void fill_csr_xcd_k(const int* __restrict__ eu, const int* __restrict__ ei,
                               int* __restrict__ cursor, int* __restrict__ col,
                               int E, int U, int N, int bucketN) {
    int xcd = blockIdx.x & (NXCD - 1);
    int lo = xcd * bucketN;
    int hi = min(N, lo + bucketN);
    int tid = (blockIdx.x >> 3) * blockDim.x + threadIdx.x;
    int stride = (gridDim.x >> 3) * blockDim.x;
    int E2 = 2 * E;
    for (int d = tid; d < E2; d += stride) {
        int r = (d < E) ? eu[d] : (ei[d - E] + U);
        if (r < lo || r >= hi) continue;
        int c = (d < E) ? (ei[d] + U) : eu[d - E];
        int pos = atomicAdd(&cursor[r], 1);
        col[pos] = c;
    }
}

// ---------- embedding init ----------

__global__ void init_y_k(const float* __restrict__ ue, const float* __restrict__ ie,
                         const float* __restrict__ dinv, float* __restrict__ y,
                         int N, int U) {
    int idx = blockIdx.x * blockDim.x + threadIdx.x;
    if (idx >= N * LAT) return;
    int node = idx >> 6;
    float e = (node < U) ? ue[idx] : ie[idx - U * LAT];
    y[idx] = dinv[node] * e;
}

__global__ void init_q_k(const float* __restrict__ ue, const float* __restrict__ ie,
                         const int* __restrict__ users, const int* __restrict__ items,
                         float* __restrict__ qacc, int B, int U) {
    int wave = blockIdx.x * (blockDim.x >> 6) + (threadIdx.x >> 6);
    int lane = threadIdx.x & 63;
    if (wave >= 2 * B) return;
    int node = (wave < B) ? users[wave] : (items[wave - B] + U);
    float e = (node < U) ? ue[node * LAT + lane] : ie[(node - U) * LAT + lane];
    qacc[wave * LAT + lane] = e;
}

// ---------- propagation: one wave per node; 4 groups x 16 lanes x float4 ----------
// Direct col loads (16 lanes share one address -> L1 broadcast; no shfl), all
// indices clamped so every lane stays active, accumulate predicated. Unroll x4
// keeps ~4KB of gathers in flight per wave to cover L2/L3 latency.

__global__ void __launch_bounds__(256)
prop4_k(const int* __restrict__ offs, const int* __restrict__ deg,
        const int* __restrict__ col, const float* __restrict__ dinv,
        const float* __restrict__ yin, float* __restrict__ yout, int N) {
    int wave = blockIdx.x * (blockDim.x >> 6) + (threadIdx.x >> 6);
    int lane = threadIdx.x & 63;
    if (wave >= N) return;
    int g = lane >> 4;        // group 0..3: neighbor j = 4*it + g
    int t = lane & 15;        // float4 slot within the row
    int start = offs[wave];
    int len = deg[wave];
    const float4* y4 = (const float4*)yin;
    const int* cp = col + start;
    int lm1 = len - 1;

    float4 a0 = {0.f,0.f,0.f,0.f}, a1 = {0.f,0.f,0.f,0.f};
    float4 a2 = {0.f,0.f,0.f,0.f}, a3 = {0.f,0.f,0.f,0.f};
    int nb = (len + 3) >> 2;   // quads; len==0 -> nb==0, no loads issued
    int it = 0;
    for (; it + 4 <= nb; it += 4) {
        int j0 = (it << 2) + g, j1 = j0 + 4, j2 = j0 + 8, j3 = j0 + 12;
        int c0 = cp[min(j0, lm1)];
        int c1 = cp[min(j1, lm1)];
        int c2 = cp[min(j2, lm1)];
        int c3 = cp[min(j3, lm1)];
        float4 v0 = y4[(size_t)c0 * 16 + t];
        float4 v1 = y4[(size_t)c1 * 16 + t];
        float4 v2 = y4[(size_t)c2 * 16 + t];
        float4 v3 = y4[(size_t)c3 * 16 + t];
        if (j0 < len) { a0.x += v0.x; a0.y += v0.y; a0.z += v0.z; a0.w += v0.w; }
        if (j1 < len) { a1.x += v1.x; a1.y += v1.y; a1.z += v1.z; a1.w += v1.w; }
        if (j2 < len) { a2.x += v2.x; a2.y += v2.y; a2.z += v2.z; a2.w += v2.w; }
        if (j3 < len) { a3.x += v3.x; a3.y += v3.y; a3.z += v3.z; a3.w += v3.w; }
    }
    for (; it < nb; ++it) {
        int j0 = (it << 2) + g;
        int c0 = cp[min(j0, lm1)];
        float4 v0 = y4[(size_t)c0 * 16 + t];
        if (j0 < len) { a0.x += v0.x; a0.y += v0.y; a0.z += v0.z; a0.w += v0.w; }
    }
    float sx = (a0.x + a1.x) + (a2.x + a3.x);
    float sy = (a0.y + a1.y) + (a2.y + a3.y);
    float sz = (a0.z + a1.z) + (a2.z + a3.z);
    float sw = (a0.w + a1.w) + (a2.w + a3.w);
    // reduce across the 4 groups (lanes t, t+16, t+32, t+48); full wave active
    sx += __shfl_xor(sx, 16); sy += __shfl_xor(sy, 16);
    sz += __shfl_xor(sz, 16); sw += __shfl_xor(sw, 16);
    sx += __shfl_xor(sx, 32); sy += __shfl_xor(sy, 32);
    sz += __shfl_xor(sz, 32); sw += __shfl_xor(sw, 32);
    if (g == 0) {
        float di = dinv[wave];
        float f = di * di;
        float4 r;
        r.x = f * sx; r.y = f * sy; r.z = f * sz; r.w = f * sw;
        ((float4*)yout)[wave * 16 + t] = r;
    }
}

// after each prop: qacc += x = y / dinv at queried nodes
__global__ void qgather_k(const float* __restrict__ y, const float* __restrict__ dinv,
                          const int* __restrict__ users, const int* __restrict__ items,
                          float* __restrict__ qacc, int B, int U) {
    int wave = blockIdx.x * (blockDim.x >> 6) + (threadIdx.x >> 6);
    int lane = threadIdx.x & 63;
    if (wave >= 2 * B) return;
    int node = (wave < B) ? users[wave] : (items[wave - B] + U);
    float di = dinv[node];
    float r = (di > 0.0f) ? (1.0f / di) : 0.0f;
    qacc[wave * LAT + lane] += y[node * LAT + lane] * r;
}

// gamma[b] = dot(qacc[b], qacc[b+B]) / 25
__global__ void gamma_k(const float* __restrict__ qacc, float* __restrict__ out, int B) {
    int wave = blockIdx.x * (blockDim.x >> 6) + (threadIdx.x >> 6);
    int lane = threadIdx.x & 63;
    if (wave >= B) return;
    float p = qacc[wave * LAT + lane] * qacc[(wave + B) * LAT + lane];
#pragma unroll
    for (int off = 32; off > 0; off >>= 1) p += __shfl_down(p, off);
    if (lane == 0) out[wave] = p * (1.0f / 25.0f);
}

extern "C" void kernel_launch(void* const* d_in, const int* in_sizes, int n_in,
                              void* d_out, int out_size, void* d_ws, size_t ws_size,
                              hipStream_t stream) {
    const float* ue = (const float*)d_in[0];
    const float* ie = (const float*)d_in[1];
    const int* edge = (const int*)d_in[2];
    const int* users = (const int*)d_in[3];
    const int* items = (const int*)d_in[4];

    const int U = in_sizes[0] / LAT;
    const int I = in_sizes[1] / LAT;
    const int N = U + I;
    const int E = in_sizes[2] / 2;
    const int B = in_sizes[3];
    const int* eu = edge;
    const int* ei = edge + E;

    char* ws = (char*)d_ws;
    size_t off = 0;
    auto alloc = [&](size_t bytes) -> void* {
        void* p = ws + off;
        off += (bytes + 255) & ~(size_t)255;
        return p;
    };
    int*   deg     = (int*)alloc((size_t)4 * N);
    int*   offs    = (int*)alloc((size_t)4 * N);
    int*   cursor  = (int*)alloc((size_t)4 * N);
    float* dinv    = (float*)alloc((size_t)4 * N);
    int*   partial = (int*)alloc(4 * 1024);
    int*   base    = (int*)alloc(4 * 1024);
    int*   col     = (int*)alloc((size_t)8 * E);           // 2E ints
    float* yA      = (float*)alloc((size_t)4 * N * LAT);
    float* yB      = (float*)alloc((size_t)4 * N * LAT);
    float* qacc    = (float*)alloc((size_t)4 * 2 * B * LAT);

    hipMemsetAsync(deg, 0, (size_t)4 * N, stream);

    const int tb = 256;
    const int bucketN = (N + NXCD - 1) / NXCD;

    count_deg_bucket_k<<<1024, tb, 0, stream>>>(eu, ei, deg, E, U, N, bucketN);

    int NB = (N + 1023) / 1024;
    scan_chunk_k<<<NB, 1024, 0, stream>>>(deg, offs, partial, N);
    scan_partial_k<<<1, 64, 0, stream>>>(partial, base, NB);
    finalize_k<<<(N + tb - 1) / tb, tb, 0, stream>>>(deg, base, offs, cursor, dinv, N);

    fill_csr_xcd_k<<<2048, tb, 0, stream>>>(eu, ei, cursor, col, E, U, N, bucketN);

    init_y_k<<<(N * LAT + tb - 1) / tb, tb, 0, stream>>>(ue, ie, dinv, yA, N, U);
    const int wpb = tb / 64;
    init_q_k<<<(2 * B + wpb - 1) / wpb, tb, 0, stream>>>(ue, ie, users, items, qacc, B, U);

    int pgrid = (N + wpb - 1) / wpb;
    int qgrid = (2 * B + wpb - 1) / wpb;

    prop4_k<<<pgrid, tb, 0, stream>>>(offs, deg, col, dinv, yA, yB, N);
    qgather_k<<<qgrid, tb, 0, stream>>>(yB, dinv, users, items, qacc, B, U);
    prop4_k<<<pgrid, tb, 0, stream>>>(offs, deg, col, dinv, yB, yA, N);
    qgather_k<<<qgrid, tb, 0, stream>>>(yA, dinv, users, items, qacc, B, U);
    prop4_k<<<pgrid, tb, 0, stream>>>(offs, deg, col, dinv, yA, yB, N);
    qgather_k<<<qgrid, tb, 0, stream>>>(yB, dinv, users, items, qacc, B, U);
    prop4_k<<<pgrid, tb, 0, stream>>>(offs, deg, col, dinv, yB, yA, N);
    qgather_k<<<qgrid, tb, 0, stream>>>(yA, dinv, users, items, qacc, B, U);

    gamma_k<<<(B + wpb - 1) / wpb, tb, 0, stream>>>(qacc, (float*)d_out, B);
}